// Round 1
// baseline (461.953 us; speedup 1.0000x reference)
//
#include <hip/hip_runtime.h>

#define B_    2
#define T_    400
#define NCH_  8
#define NBIN_ 512
#define NBAND_ 40
#define NPV_  64
#define C2_   64

// LDS float layout:
//  xsr  [8][513]    @ 0      (4104)
//  xsi  [8][513]    @ 4104   (4104)
//  invt [512]       @ 8208   (512)
//  bmt/bc 2560xf2   @ 8720   (5120)
//  dsinv[40]        @ 13840  (40)
//  wt (4096 float2) overlays xsr+xsi after the f-loop (needs 8192 floats <= 8208)
// total 13880 floats = 55520 B -> 2 WG/CU on 160KB LDS

__global__ __launch_bounds__(256, 2) void pv_main(
    const float* __restrict__ br, const float* __restrict__ bi,
    const float* __restrict__ bmr, const float* __restrict__ bmi,
    const float* __restrict__ c2pr, const float* __restrict__ c2pi,
    float* __restrict__ out)
{
  __shared__ __align__(16) float smem[13880];
  float*  xsr  = smem;
  float*  xsi  = smem + 4104;
  float*  invt = smem + 8208;
  float2* bmt  = (float2*)(smem + 8720);
  float*  dsinv = smem + 13840;
  float2* wt   = (float2*)smem;

  const int bt  = blockIdx.x;        // b*T + t
  const int tid = threadIdx.x;
  const float* pr  = br + (size_t)bt * (NCH_*NBIN_);
  const float* pim = bi + (size_t)bt * (NCH_*NBIN_);

  // ---- stage x into LDS (SoA, padded stride 513) ----
  const float4* pr4 = (const float4*)pr;
  const float4* pi4 = (const float4*)pim;
  for (int v = tid; v < 1024; v += 256) {
    float4 r = pr4[v], q = pi4[v];
    int c = v >> 7;            // 128 float4 per channel
    int f = (v & 127) << 2;
    float* dr = xsr + c*513 + f;
    float* di = xsi + c*513 + f;
    dr[0]=r.x; dr[1]=r.y; dr[2]=r.z; dr[3]=r.w;
    di[0]=q.x; di[1]=q.y; di[2]=q.z; di[3]=q.w;
  }
  __syncthreads();

  // ---- per-bin inverse trace ----
  for (int f = tid; f < NBIN_; f += 256) {
    float s = 0.f;
    #pragma unroll
    for (int c = 0; c < NCH_; c++) {
      float a = xsr[c*513+f], b2 = xsi[c*513+f];
      s = fmaf(a, a, s); s = fmaf(b2, b2, s);
    }
    invt[f] = __builtin_amdgcn_rcpf(fmaxf(s, 1e-20f));
  }

  const int p  = tid & 63;
  const int kg = tid >> 6;           // wave-uniform
  const int kbase = kg * 10;
  const int ii = p >> 3, jj = p & 7;
  const bool isdiag = (ii == jj);
  const float* xr_i = xsr + ii*513;
  const float* xi_i = xsi + ii*513;
  const float* xr_j = xsr + jj*513;
  const float* xi_j = xsi + jj*513;

  float2 acc[10];
  #pragma unroll
  for (int m = 0; m < 10; m++) acc[m] = make_float2(0.f, 0.f);

  __syncthreads();                    // invt ready

  // rolling window of unnormalized c[p,f] = x_i[f] * conj(x_j[f])
  float2 cm1, c0;
  {
    float a = xr_i[0], b2 = xi_i[0], cx = xr_j[0], d = xi_j[0];
    cm1 = make_float2(fmaf(a,cx,b2*d), fmaf(b2,cx,-a*d));
    a = xr_i[1]; b2 = xi_i[1]; cx = xr_j[1]; d = xi_j[1];
    c0  = make_float2(fmaf(a,cx,b2*d), fmaf(b2,cx,-a*d));
  }

  for (int tile = 0; tile < 8; tile++) {
    const int f0 = tile << 6;
    __syncthreads();                  // previous tile fully consumed
    for (int j = tid; j < 2560; j += 256) {
      bmt[j] = make_float2(bmr[f0*40 + j], bmi[f0*40 + j]);
    }
    __syncthreads();
    const int fs = (tile == 0) ? 1 : f0;
    const int fe = (tile == 7) ? 510 : (f0 + 63);
    for (int f = fs; f <= fe; f++) {
      float a = xr_i[f+1], b2 = xi_i[f+1], cx = xr_j[f+1], d = xi_j[f+1];
      float2 cp1 = make_float2(fmaf(a,cx,b2*d), fmaf(b2,cx,-a*d));
      // q = conj(c[f-1]) * c[f+1]   (phase invariant under trace normalization)
      float qr = fmaf(cm1.x, cp1.x,  cm1.y*cp1.y);
      float qi = fmaf(cm1.x, cp1.y, -cm1.y*cp1.x);
      // unit phasor u = q/|q|, robust against underflow; atan2(0,0)=0 -> (1,0)
      float am = fmaxf(fmaxf(fabsf(qr), fabsf(qi)), 1e-30f);
      float s  = __builtin_amdgcn_rcpf(am);
      float q1 = qr*s, q2 = qi*s;
      float n2 = fmaf(q1, q1, q2*q2);
      float rn = __builtin_amdgcn_rsqf(n2);
      bool ok = (n2 > 0.f);
      float ur = ok ? q1*rn : 1.f;
      float ui = ok ? q2*rn : 0.f;
      float it  = invt[f];
      float mag = __builtin_amdgcn_sqrtf(fmaf(c0.x, c0.x, c0.y*c0.y)) * it;
      float ar2 = isdiag ? (c0.x * it) : (mag * ur);
      float ai2 = isdiag ? 0.f        : (mag * ui);
      const float2* brow = bmt + (f - f0)*40 + kbase;
      #pragma unroll
      for (int m = 0; m < 10; m++) {
        float2 bv = brow[m];
        acc[m].x = fmaf(ar2, bv.x, fmaf(-ai2, bv.y, acc[m].x));
        acc[m].y = fmaf(ar2, bv.y, fmaf( ai2, bv.x, acc[m].y));
      }
      if (f == 1) {                   // emit bin 0 with u from (c0,c2)
        float it0 = invt[0];
        float m0 = __builtin_amdgcn_sqrtf(fmaf(cm1.x, cm1.x, cm1.y*cm1.y)) * it0;
        float a0r = isdiag ? (cm1.x * it0) : (m0 * ur);
        float a0i = isdiag ? 0.f           : (m0 * ui);
        const float2* b0 = bmt + kbase;   // tile 0, row 0
        #pragma unroll
        for (int m = 0; m < 10; m++) {
          float2 bv = b0[m];
          acc[m].x = fmaf(a0r, bv.x, fmaf(-a0i, bv.y, acc[m].x));
          acc[m].y = fmaf(a0r, bv.y, fmaf( a0i, bv.x, acc[m].y));
        }
      }
      if (f == 510) {                 // emit bin 511 with u from (c509,c511)
        float itL = invt[511];
        float mL = __builtin_amdgcn_sqrtf(fmaf(cp1.x, cp1.x, cp1.y*cp1.y)) * itL;
        float aLr = isdiag ? (cp1.x * itL) : (mL * ur);
        float aLi = isdiag ? 0.f           : (mL * ui);
        const float2* bL = bmt + (511 - f0)*40 + kbase;  // tile 7, row 63
        #pragma unroll
        for (int m = 0; m < 10; m++) {
          float2 bv = bL[m];
          acc[m].x = fmaf(aLr, bv.x, fmaf(-aLi, bv.y, acc[m].x));
          acc[m].y = fmaf(aLr, bv.y, fmaf( aLi, bv.x, acc[m].y));
        }
      }
      cm1 = c0; c0 = cp1;
    }
  }

  // ---- epilogue: dsum normalize + fold c2p projection (IIR commutes with it) ----
  __syncthreads();                    // f-loop done: bmt -> bc, xs region -> wt
  float2* bc = bmt;
  #pragma unroll
  for (int m = 0; m < 10; m++) bc[(kbase+m)*64 + p] = acc[m];
  for (int idx = tid; idx < 4096; idx += 256) {
    // transpose c2p into [c][p] so epilogue reads are conflict-free
    wt[(idx & 63)*64 + (idx >> 6)] = make_float2(c2pr[idx], c2pi[idx]);
  }
  __syncthreads();
  if (tid < 40) {
    float ds = 0.f;
    #pragma unroll
    for (int i2 = 0; i2 < 8; i2++) ds += bc[tid*64 + i2*9].x;
    dsinv[tid] = 1.0f / fmaxf(ds, 1e-20f);   // clip then divide (matches jnp.clip)
  }
  __syncthreads();
  float zacc[10];
  #pragma unroll
  for (int m = 0; m < 10; m++) zacc[m] = 0.f;
  for (int c = 0; c < 64; c++) {
    float2 w = wt[c*64 + p];          // lanes consecutive -> 2-way (free)
    #pragma unroll
    for (int m = 0; m < 10; m++) {
      float2 bv = bc[(kbase+m)*64 + c];  // wave-uniform -> broadcast
      zacc[m] = fmaf(w.x, bv.x, fmaf(-w.y, bv.y, zacc[m]));
    }
  }
  float* op = out + (size_t)bt * (NBAND_*NPV_);
  #pragma unroll
  for (int m = 0; m < 10; m++) {
    op[(kbase+m)*64 + p] = zacc[m] * dsinv[kbase+m];
  }
}

// In-place IIR over t on the already-projected real pv (valid since the
// projection is t-independent and real-linear, and a/(1-a) are real).
__global__ __launch_bounds__(256) void pv_iir(float* __restrict__ z,
                                              const float* __restrict__ tau)
{
  int tid = blockIdx.x * 256 + threadIdx.x;   // 5120 threads
  int p = tid & 63;
  int g = tid >> 6;                           // b*NBAND + k
  int k = g % NBAND_;
  int b = g / NBAND_;
  float a  = tau[k];
  float om = 1.0f - a;
  float y = 0.f;
  size_t idx = ((size_t)b * T_ * NBAND_ + k) * 64 + p;
  const size_t stride = (size_t)NBAND_ * 64;
  #pragma unroll 8
  for (int t = 0; t < T_; t++) {
    float v = z[idx];
    y = fmaf(a, y, om * v);
    z[idx] = y;
    idx += stride;
  }
}

extern "C" void kernel_launch(void* const* d_in, const int* in_sizes, int n_in,
                              void* d_out, int out_size, void* d_ws, size_t ws_size,
                              hipStream_t stream)
{
  const float* br   = (const float*)d_in[0];
  const float* bi   = (const float*)d_in[1];
  const float* bmr  = (const float*)d_in[2];
  const float* bmi  = (const float*)d_in[3];
  const float* c2pr = (const float*)d_in[4];
  const float* c2pi = (const float*)d_in[5];
  const float* tau  = (const float*)d_in[6];
  float* out = (float*)d_out;

  hipLaunchKernelGGL(pv_main, dim3(B_*T_), dim3(256), 0, stream,
                     br, bi, bmr, bmi, c2pr, c2pi, out);
  hipLaunchKernelGGL(pv_iir, dim3((B_*NBAND_*NPV_)/256), dim3(256), 0, stream,
                     out, tau);
}

// Round 2
// 271.443 us; speedup vs baseline: 1.7018x; 1.7018x over previous
//
#include <hip/hip_runtime.h>

#define B_    2
#define T_    400
#define NCH_  8
#define NBIN_ 512
#define NBAND_ 40
#define NPV_  64

// LDS float layout (total 10080 floats = 40,320 B -> 4 blocks/CU):
//  xsr [8][513] @0 (4104) | xsi @4104 (4104)   -> x staging, dead after main loop
//  invt[512]    @8208
//  bmt  [17][40] float2 @8720 (1360 floats)    -> per-16-bin-tile band matrix
// epilogue overlays in [0..8208):
//  bc [40][64] float2 @0 (5120) | wtr[64][17] @5120 (1088) | wti @6208 (1088) | dsinv @7296 (40)

__global__ __launch_bounds__(256, 4) void pv_main(
    const float* __restrict__ br, const float* __restrict__ bi,
    const float* __restrict__ bmr, const float* __restrict__ bmi,
    const float* __restrict__ c2pr, const float* __restrict__ c2pi,
    float* __restrict__ out)
{
  __shared__ __align__(16) float smem[10080];
  float*  xsr  = smem;
  float*  xsi  = smem + 4104;
  float*  invt = smem + 8208;
  float2* bmt  = (float2*)(smem + 8720);

  const int bt  = blockIdx.x;
  const int tid = threadIdx.x;
  const float* pr  = br + (size_t)bt * (NCH_*NBIN_);
  const float* pim = bi + (size_t)bt * (NCH_*NBIN_);

  // ---- stage x into LDS (SoA, padded stride 513) ----
  const float4* pr4 = (const float4*)pr;
  const float4* pi4 = (const float4*)pim;
  for (int v = tid; v < 1024; v += 256) {
    float4 rr = pr4[v], qq = pi4[v];
    int c = v >> 7;
    int f = (v & 127) << 2;
    float* dr = xsr + c*513 + f;
    float* di = xsi + c*513 + f;
    dr[0]=rr.x; dr[1]=rr.y; dr[2]=rr.z; dr[3]=rr.w;
    di[0]=qq.x; di[1]=qq.y; di[2]=qq.z; di[3]=qq.w;
  }
  __syncthreads();

  // ---- per-bin inverse trace ----
  for (int f = tid; f < NBIN_; f += 256) {
    float s = 0.f;
    #pragma unroll
    for (int c = 0; c < NCH_; c++) {
      float a = xsr[c*513+f], b2 = xsi[c*513+f];
      s = fmaf(a, a, s); s = fmaf(b2, b2, s);
    }
    invt[f] = __builtin_amdgcn_rcpf(fmaxf(s, 1e-20f));
  }

  // ---- lane decode: lane = 2*entity + h;  entity<28: pair (i<j), else dual-diag ----
  const int lane = tid & 63;
  const int kg   = tid >> 6;          // wave-uniform k-group (10 bands)
  const int kbase = kg * 10;
  const int h = lane & 1;
  const int e = lane >> 1;
  const bool isdual = (e >= 28);
  int i = 0, ee = e;
  if (!isdual) {
    while (ee >= 7 - i) { ee -= 7 - i; i++; }
  }
  int j;
  if (isdual) { i = 2 * (e - 28); j = i + 1; }
  else        { j = i + 1 + ee; }
  const float* Ar = xsr + i*513;
  const float* Ai = xsi + i*513;
  const float* Br = xsr + j*513;
  const float* Bi = xsi + j*513;
  const int r = 1 + h;                 // bin-parity class

  float S[40];
  #pragma unroll
  for (int m = 0; m < 40; m++) S[m] = 0.f;

  // W = pair: c[f] = x_i*conj(x_j) ; dual: (|x_d1|^2, |x_d2|^2)
  auto cwin = [&](int f) -> float2 {
    float a1 = Ar[f], b1 = Ai[f], a2 = Br[f], b2 = Bi[f];
    float X  = isdual ? a1 : a2;
    float Y  = isdual ? b1 : b2;
    float P  = isdual ? a2 : b1;
    float Qs = isdual ? b2 : -a1;
    return make_float2(fmaf(a1, X, b1 * Y), fmaf(P, a2, Qs * b2));
  };
  auto phasor = [&](float2 Wm, float2 Wp, float& ur, float& ui) {
    float qr = fmaf(Wm.x, Wp.x, Wm.y * Wp.y);
    float qi = fmaf(Wm.x, Wp.y, -(Wm.y * Wp.x));
    float am = fmaxf(fmaxf(fabsf(qr), fabsf(qi)), 1e-30f);
    float sc = __builtin_amdgcn_rcpf(am);
    float q1 = qr * sc, q2 = qi * sc;
    float n2 = fmaf(q1, q1, q2 * q2);
    float rn = __builtin_amdgcn_rsqf(n2);
    bool ok = n2 > 0.f;
    ur = ok ? q1 * rn : 1.f;
    ui = ok ? q2 * rn : 0.f;
  };
  auto mults = [&](float2 Wc, float it, float ur, float ui, float& P1, float& P2) {
    float mg = __builtin_amdgcn_sqrtf(fmaf(Wc.x, Wc.x, Wc.y * Wc.y)) * it;
    P1 = isdual ? Wc.x * it : mg * ur;
    P2 = isdual ? Wc.y * it : mg * ui;
  };
  auto emit = [&](float P1, float P2, const float2* brow) {
    const float4* b4p = (const float4*)brow;   // 16B-aligned by layout
    #pragma unroll
    for (int m = 0; m < 5; m++) {
      float4 bb = b4p[m];
      S[8*m+0] = fmaf(P1, bb.x, S[8*m+0]);
      S[8*m+1] = fmaf(P2, bb.y, S[8*m+1]);
      S[8*m+2] = fmaf(P1, bb.y, S[8*m+2]);
      S[8*m+3] = fmaf(P2, bb.x, S[8*m+3]);
      S[8*m+4] = fmaf(P1, bb.z, S[8*m+4]);
      S[8*m+5] = fmaf(P2, bb.w, S[8*m+5]);
      S[8*m+6] = fmaf(P1, bb.w, S[8*m+6]);
      S[8*m+7] = fmaf(P2, bb.z, S[8*m+7]);
    }
  };

  // ---- main loop: 32 tiles of 16 bins; lane covers f = 16t + r + 2m ----
  for (int t = 0; t < 32; t++) {
    __syncthreads();                         // prev bmt consumed (t=0: invt ready)
    const int gb = 640 * t;                  // (16t)*40
    for (int u = tid; u < 680; u += 256) {   // rows [16t .. 16t+16]
      int gc = gb + u; gc = gc < 20480 ? gc : 20479;
      bmt[u] = make_float2(bmr[gc], bmi[gc]);
    }
    __syncthreads();
    const int f0 = 16 * t + r;
    float2 W0 = cwin(f0 - 1), W1 = cwin(f0), W2 = cwin(f0 + 1);
    if (t == 0) {                            // bin 0: u from conj(c[0])*c[2] (h==0 lanes)
      float ur, ui; phasor(W0, W2, ur, ui);
      float P1, P2; mults(W0, invt[0], ur, ui, P1, P2);
      if (h == 0) emit(P1, P2, bmt + kbase);
    }
    const int mmax = (t == 31) ? 7 : 8;
    for (int m = 0; m < mmax; m++) {
      const int f = f0 + 2 * m;
      float ur, ui; phasor(W0, W2, ur, ui);
      float P1, P2; mults(W1, invt[f], ur, ui, P1, P2);
      emit(P1, P2, bmt + (f - 16 * t) * 40 + kbase);
      if (m + 1 < mmax) { W0 = W2; W1 = cwin(f + 2); W2 = cwin(f + 3); }
    }
    if (t == 31) {                           // bin 511: u from conj(c[509])*c[511] (h==1 lanes)
      float2 Wa = cwin(509), Wc = cwin(511);
      float ur, ui; phasor(Wa, Wc, ur, ui);
      float P1, P2; mults(Wc, invt[511], ur, ui, P1, P2);
      if (h == 1) emit(P1, P2, bmt + 15 * 40 + kbase);
    }
  }

  // ---- epilogue ----
  __syncthreads();                           // x region dead; safe to overlay
  #pragma unroll
  for (int m = 0; m < 40; m++) S[m] += __shfl_xor(S[m], 1);   // combine parity halves

  float2* bc   = (float2*)smem;              // [40][64]
  float*  wtr  = smem + 5120;                // [64][17]
  float*  wti  = smem + 6208;                // [64][17]
  float*  dsinv = smem + 7296;               // [40]
  {
    int pidx = isdual ? ((h ? j : i) * 9) : (h ? j * 8 + i : i * 8 + j);
    #pragma unroll
    for (int m = 0; m < 10; m++) {
      float s0 = S[4*m], s1 = S[4*m+1], s2 = S[4*m+2], s3 = S[4*m+3];
      float vx = isdual ? (h ? s3 : s0) : (h ? s0 + s1 : s0 - s1);
      float vy = isdual ? (h ? s1 : s2) : (h ? s2 - s3 : s2 + s3);
      bc[(kbase + m) * 64 + pidx] = make_float2(vx, vy);
    }
  }
  __syncthreads();
  if (tid < 40) {
    float ds = 0.f;
    #pragma unroll
    for (int d = 0; d < 8; d++) ds += bc[tid * 64 + d * 9].x;
    dsinv[tid] = 1.0f / fmaxf(ds, 1e-20f);
  }
  float zacc[10];
  #pragma unroll
  for (int m = 0; m < 10; m++) zacc[m] = 0.f;
  const int p2 = lane;                       // output pv row
  for (int ch = 0; ch < 4; ch++) {
    __syncthreads();                         // dsinv/bc ready; prev c2p chunk consumed
    for (int u = tid; u < 1024; u += 256) {
      int pr2 = u >> 4, cl = u & 15;
      int gi = pr2 * 64 + ch * 16 + cl;
      wtr[pr2 * 17 + cl] = c2pr[gi];
      wti[pr2 * 17 + cl] = c2pi[gi];
    }
    __syncthreads();
    #pragma unroll
    for (int cl = 0; cl < 16; cl++) {
      float wr  = wtr[p2 * 17 + cl];
      float wi2 = wti[p2 * 17 + cl];
      int c = ch * 16 + cl;
      #pragma unroll
      for (int m = 0; m < 10; m++) {
        float2 v = bc[(kbase + m) * 64 + c];
        zacc[m] = fmaf(wr, v.x, fmaf(-wi2, v.y, zacc[m]));
      }
    }
  }
  float* op = out + (size_t)bt * (NBAND_*NPV_);
  #pragma unroll
  for (int m = 0; m < 10; m++) op[(kbase + m) * 64 + p2] = zacc[m] * dsinv[kbase + m];
}

// Chunked-scan IIR over t (in place on projected pv; projection commutes with IIR).
// Block = (b,k): 512 threads = 64 p x 8 chunks of 50 frames, registers hold the chunk.
__global__ __launch_bounds__(512) void pv_iir2(float* __restrict__ z,
                                               const float* __restrict__ tau)
{
  __shared__ float gsh[8][64];
  const int bk = blockIdx.x;
  const int k = bk % NBAND_;
  const int b = bk / NBAND_;
  const float a  = tau[k];
  const float om = 1.0f - a;
  const int p = threadIdx.x & 63;
  const int c = threadIdx.x >> 6;
  const size_t stride = (size_t)NBAND_ * 64;
  size_t idx0 = (size_t)b * (T_ * NBAND_ * 64) + (size_t)(c * 50) * stride + k * 64 + p;

  float y[50];
  float acc = 0.f;
  #pragma unroll
  for (int i2 = 0; i2 < 50; i2++) {
    float v = z[idx0 + (size_t)i2 * stride];
    acc = fmaf(a, acc, om * v);
    y[i2] = acc;
  }
  gsh[c][p] = acc;
  __syncthreads();
  // A = a^50 = a^32 * a^16 * a^2
  float a2 = a*a, a4 = a2*a2, a8 = a4*a4, a16 = a8*a8, a32 = a16*a16;
  float A = a32 * a16 * a2;
  float H = 0.f;
  #pragma unroll
  for (int d = 0; d < 7; d++) {
    if (d < c) H = fmaf(A, H, gsh[d][p]);
  }
  float w = a;
  #pragma unroll
  for (int i2 = 0; i2 < 50; i2++) {
    z[idx0 + (size_t)i2 * stride] = fmaf(w, H, y[i2]);
    w *= a;
  }
}

extern "C" void kernel_launch(void* const* d_in, const int* in_sizes, int n_in,
                              void* d_out, int out_size, void* d_ws, size_t ws_size,
                              hipStream_t stream)
{
  const float* br   = (const float*)d_in[0];
  const float* bi   = (const float*)d_in[1];
  const float* bmr  = (const float*)d_in[2];
  const float* bmi  = (const float*)d_in[3];
  const float* c2pr = (const float*)d_in[4];
  const float* c2pi = (const float*)d_in[5];
  const float* tau  = (const float*)d_in[6];
  float* out = (float*)d_out;

  hipLaunchKernelGGL(pv_main, dim3(B_*T_), dim3(256), 0, stream,
                     br, bi, bmr, bmi, c2pr, c2pi, out);
  hipLaunchKernelGGL(pv_iir2, dim3(B_*NBAND_), dim3(512), 0, stream,
                     out, tau);
}

// Round 3
// 170.861 us; speedup vs baseline: 2.7037x; 1.5887x over previous
//
#include <hip/hip_runtime.h>

#define B_    2
#define T_    400
#define NCH_  8
#define NBIN_ 512
#define NBAND_ 40
#define NPV_  64

using short8  = __attribute__((ext_vector_type(8))) short;
using float4v = __attribute__((ext_vector_type(4))) float;

// bf16 round-to-nearest-even pack of two floats into one dword (lo=x, hi=y)
static __device__ inline unsigned pkbf(float x, float y) {
  union { float f; unsigned u; } a, b;
  a.f = x; b.f = y;
  unsigned ra = a.u + 0x7fffu + ((a.u >> 16) & 1u);
  unsigned rb = b.u + 0x7fffu + ((b.u >> 16) & 1u);
  return (ra >> 16) | (rb & 0xffff0000u);
}

// ---------------- prep: dsinv + B-fragment packing into d_ws ----------------
// ws layout: [0..255] floats: dsinv[40] (rest pad). frags at byte 1024:
//   frag F = ((g*3+n)*32 + s)*64 + lane, 16 B each; total 12288 frags = 196608 B.
__global__ __launch_bounds__(256) void pv_prep(
    const float* __restrict__ bmr, const float* __restrict__ bmi,
    float* __restrict__ ws)
{
  const int tid = threadIdx.x;
  if (blockIdx.x == 0) {
    __shared__ float sds[256];
    int k = tid & 63, part = tid >> 6;      // 4 partials x 64 (only k<40 valid)
    float s = 0.f;
    if (k < NBAND_) {
      for (int f = part * 128; f < part * 128 + 128; f++) s += bmr[f * 40 + k];
    }
    sds[tid] = s;
    __syncthreads();
    if (tid < NBAND_) {
      float t = sds[tid] + sds[tid + 64] + sds[tid + 128] + sds[tid + 192];
      ws[tid] = 1.0f / fmaxf(t, 1e-20f);
    }
  } else {
    int F = (blockIdx.x - 1) * 256 + tid;   // 0..12287
    int l = F & 63;
    int rest = F >> 6;
    int s5 = rest & 31;
    int gn = rest >> 5;
    int n = gn % 3, g = gn / 3;
    int k = n * 16 + (l & 15);
    unsigned dw[4];
    #pragma unroll
    for (int t2 = 0; t2 < 4; t2++) {
      float v0 = 0.f, v1 = 0.f;
      if (k < NBAND_) {
        int kd = s5 * 32 + (l >> 4) * 8 + 2 * t2;   // even slot
        int f = kd >> 1;
        if (g == 0) { v0 = bmr[f * 40 + k]; v1 = -bmi[f * 40 + k]; }
        else        { v0 = bmi[f * 40 + k]; v1 =  bmr[f * 40 + k]; }
      }
      dw[t2] = pkbf(v0, v1);
    }
    uint4* dst = (uint4*)((char*)ws + 1024);
    dst[F] = make_uint4(dw[0], dw[1], dw[2], dw[3]);
  }
}

// ---------------- main kernel ----------------
// LDS: smem[0..8223]  : vsh (float2 [8][514])  -- epilogue overlays:
//                       bcsh float2[48][65] (6240 f) + wtr/wti [64][9]x2 (1152 f)
//      smem[8224..8735]: sc[512]  (phase A only)
// total 8736 floats = 34,944 B -> 4 blocks/CU
__global__ __launch_bounds__(256, 4) void pv_main(
    const float* __restrict__ br, const float* __restrict__ bi,
    const float* __restrict__ c2pr, const float* __restrict__ c2pi,
    const float* __restrict__ ws, float* __restrict__ out)
{
  __shared__ __align__(16) float smem[8736];
  float2* vsh = (float2*)smem;            // [c][f] stride 514
  float*  sc  = smem + 8224;

  const int bt  = blockIdx.x;
  const int tid = threadIdx.x;
  const float* pr  = br + (size_t)bt * (NCH_ * NBIN_);
  const float* pim = bi + (size_t)bt * (NCH_ * NBIN_);

  // ---- phase A1: sc[f] = rsqrt(clip(trace)) ----
  for (int f = tid; f < NBIN_; f += 256) {
    float s = 0.f;
    #pragma unroll
    for (int c = 0; c < NCH_; c++) {
      float a = pr[c * 512 + f], b2 = pim[c * 512 + f];
      s = fmaf(a, a, s); s = fmaf(b2, b2, s);
    }
    sc[f] = __builtin_amdgcn_rsqf(fmaxf(s, 1e-20f));
  }
  __syncthreads();

  // ---- phase A2: vsh[c][f] = |x_c[f]| * normalize(G_c[f]) * sc[f] ----
  for (int u = 0; u < 16; u++) {
    int idx = u * 256 + tid;
    int c = idx >> 9, f = idx & 511;
    int fm = (f == 0) ? 0 : ((f == 511) ? 509 : f - 1);
    int fp = (f == 0) ? 2 : ((f == 511) ? 511 : f + 1);
    const float* cr = pr + c * 512;
    const float* ci = pim + c * 512;
    float xrm = cr[fm], xim = ci[fm];
    float xrp = cr[fp], xip = ci[fp];
    float xr = cr[f],   xi = ci[f];
    float Gr = fmaf(xrm, xrp,  xim * xip);     // conj(x[fm]) * x[fp]
    float Gi = fmaf(xrm, xip, -(xim * xrp));
    float am = fmaxf(fmaxf(fabsf(Gr), fabsf(Gi)), 1e-30f);
    float rc = __builtin_amdgcn_rcpf(am);
    float q1 = Gr * rc, q2 = Gi * rc;
    float n2 = fmaf(q1, q1, q2 * q2);
    float rn = __builtin_amdgcn_rsqf(n2);
    bool ok = n2 > 0.f;
    float ur = ok ? q1 * rn : 1.f;
    float ui = ok ? q2 * rn : 0.f;
    float mg = __builtin_amdgcn_sqrtf(fmaf(xr, xr, xi * xi)) * sc[f];
    vsh[c * 514 + f] = make_float2(mg * ur, mg * ui);
  }
  __syncthreads();

  // ---- main GEMM: C[p][k] = sum_f adj[p][f]*bm[f][k], adj = v_i * conj(v_j) ----
  const int w    = tid >> 6;       // wave id -> M-tile
  const int lane = tid & 63;
  const int m16  = lane & 15;
  const int quad = lane >> 4;
  const int p    = w * 16 + m16;
  const int ich  = p >> 3, jch = p & 7;
  const float4* Av = (const float4*)(vsh + ich * 514 + quad * 4);
  const float4* Bv = (const float4*)(vsh + jch * 514 + quad * 4);
  const float4* BF = ((const float4*)((const char*)ws + 1024)) + lane;

  float4v acc[6];
  #pragma unroll
  for (int g = 0; g < 6; g++) acc[g] = (float4v){0.f, 0.f, 0.f, 0.f};

  #pragma unroll 2
  for (int s = 0; s < 32; s++) {
    float4 a01 = Av[s * 8];       // (r[f],i[f],r[f+1],i[f+1]), f = s*16+quad*4
    float4 a23 = Av[s * 8 + 1];
    float4 b01 = Bv[s * 8];
    float4 b23 = Bv[s * 8 + 1];
    // a = v_i * conj(v_j)
    float ar0 = fmaf(a01.x, b01.x,  a01.y * b01.y);
    float ai0 = fmaf(a01.y, b01.x, -(a01.x * b01.y));
    float ar1 = fmaf(a01.z, b01.z,  a01.w * b01.w);
    float ai1 = fmaf(a01.w, b01.z, -(a01.z * b01.w));
    float ar2 = fmaf(a23.x, b23.x,  a23.y * b23.y);
    float ai2 = fmaf(a23.y, b23.x, -(a23.x * b23.y));
    float ar3 = fmaf(a23.z, b23.z,  a23.w * b23.w);
    float ai3 = fmaf(a23.w, b23.z, -(a23.z * b23.w));
    uint4 au = make_uint4(pkbf(ar0, ai0), pkbf(ar1, ai1),
                          pkbf(ar2, ai2), pkbf(ar3, ai3));
    short8 afrag = __builtin_bit_cast(short8, au);
    #pragma unroll
    for (int gn = 0; gn < 6; gn++) {
      float4 rawb = BF[(gn * 32 + s) * 64];
      short8 bfrag = __builtin_bit_cast(short8, rawb);
      acc[gn] = __builtin_amdgcn_mfma_f32_16x16x32_bf16(afrag, bfrag, acc[gn], 0, 0, 0);
    }
  }

  // ---- epilogue: store C to LDS, fp32 c2p projection, dsinv scale ----
  __syncthreads();                 // vsh dead; overlay bcsh/wt
  float2* bcsh = (float2*)smem;    // [k=48][c=64] stride 65
  float*  wtr  = smem + 6240;      // [64][9]
  float*  wti  = smem + 6240 + 576;
  #pragma unroll
  for (int n = 0; n < 3; n++) {
    int k = n * 16 + m16;
    #pragma unroll
    for (int r = 0; r < 4; r++) {
      int c = w * 16 + quad * 4 + r;
      bcsh[k * 65 + c] = make_float2(acc[n][r], acc[3 + n][r]);
    }
  }

  const int kbase = w * 10;
  float zacc[10];
  #pragma unroll
  for (int m = 0; m < 10; m++) zacc[m] = 0.f;

  for (int ch = 0; ch < 8; ch++) {
    __syncthreads();
    for (int u2 = tid; u2 < 512; u2 += 256) {
      int p2 = u2 >> 3, cl = u2 & 7;
      int gi = p2 * 64 + ch * 8 + cl;
      wtr[p2 * 9 + cl] = c2pr[gi];
      wti[p2 * 9 + cl] = c2pi[gi];
    }
    __syncthreads();
    #pragma unroll
    for (int cl = 0; cl < 8; cl++) {
      float wr = wtr[lane * 9 + cl];
      float wi = wti[lane * 9 + cl];
      int c = ch * 8 + cl;
      #pragma unroll
      for (int m = 0; m < 10; m++) {
        float2 v = bcsh[(kbase + m) * 65 + c];
        zacc[m] = fmaf(wr, v.x, fmaf(-wi, v.y, zacc[m]));
      }
    }
  }
  float* op = out + (size_t)bt * (NBAND_ * NPV_);
  #pragma unroll
  for (int m = 0; m < 10; m++) {
    op[(kbase + m) * 64 + lane] = zacc[m] * ws[kbase + m];
  }
}

// ---------------- IIR: chunked scan, 320 blocks x 256 thr, chunk=25 ----------------
__global__ __launch_bounds__(256) void pv_iir3(float* __restrict__ z,
                                               const float* __restrict__ tau)
{
  __shared__ float gsh[16][16];
  const int pg = blockIdx.x & 3;
  const int bk = blockIdx.x >> 2;
  const int k = bk % NBAND_;
  const int b = bk / NBAND_;
  const float a  = tau[k];
  const float om = 1.0f - a;
  const int c  = threadIdx.x >> 4;          // chunk 0..15
  const int pl = threadIdx.x & 15;
  const int p  = pg * 16 + pl;
  const size_t stride = (size_t)NBAND_ * 64;
  size_t idx0 = (size_t)b * (T_ * NBAND_ * 64) + (size_t)(c * 25) * stride + k * 64 + p;

  float y[25];
  float accv = 0.f;
  #pragma unroll
  for (int i = 0; i < 25; i++) {
    float v = z[idx0 + (size_t)i * stride];
    accv = fmaf(a, accv, om * v);
    y[i] = accv;
  }
  gsh[c][pl] = accv;
  __syncthreads();
  float a2 = a * a, a4 = a2 * a2, a8 = a4 * a4, a16 = a8 * a8;
  float A = a16 * a8 * a;                   // a^25
  float H = 0.f;
  #pragma unroll
  for (int d = 0; d < 15; d++) {
    if (d < c) H = fmaf(A, H, gsh[d][pl]);
  }
  float wp = a;
  #pragma unroll
  for (int i = 0; i < 25; i++) {
    z[idx0 + (size_t)i * stride] = fmaf(wp, H, y[i]);
    wp *= a;
  }
}

extern "C" void kernel_launch(void* const* d_in, const int* in_sizes, int n_in,
                              void* d_out, int out_size, void* d_ws, size_t ws_size,
                              hipStream_t stream)
{
  const float* br   = (const float*)d_in[0];
  const float* bi   = (const float*)d_in[1];
  const float* bmr  = (const float*)d_in[2];
  const float* bmi  = (const float*)d_in[3];
  const float* c2pr = (const float*)d_in[4];
  const float* c2pi = (const float*)d_in[5];
  const float* tau  = (const float*)d_in[6];
  float* out = (float*)d_out;
  float* ws  = (float*)d_ws;

  hipLaunchKernelGGL(pv_prep, dim3(49), dim3(256), 0, stream, bmr, bmi, ws);
  hipLaunchKernelGGL(pv_main, dim3(B_ * T_), dim3(256), 0, stream,
                     br, bi, c2pr, c2pi, ws, out);
  hipLaunchKernelGGL(pv_iir3, dim3(B_ * NBAND_ * 4), dim3(256), 0, stream,
                     out, tau);
}

// Round 4
// 122.930 us; speedup vs baseline: 3.7579x; 1.3899x over previous
//
#include <hip/hip_runtime.h>

#define B_    2
#define T_    400
#define NCH_  8
#define NBIN_ 512
#define NBAND_ 40
#define NPV_  64

using short8  = __attribute__((ext_vector_type(8))) short;
using float4v = __attribute__((ext_vector_type(4))) float;

// bf16 round-to-nearest-even pack of two floats into one dword (lo=x, hi=y)
static __device__ inline unsigned pkbf(float x, float y) {
  union { float f; unsigned u; } a, b;
  a.f = x; b.f = y;
  unsigned ra = a.u + 0x7fffu + ((a.u >> 16) & 1u);
  unsigned rb = b.u + 0x7fffu + ((b.u >> 16) & 1u);
  return (ra >> 16) | (rb & 0xffff0000u);
}

// ws layout (bytes):
//   [0..159]              : dsinv[40] floats
//   [1024, 1024+196608)   : band B-frags: F=((g*3+n)*32+s)*64+lane, uint4 each
//   [197632, 197632+16384): epi  B-frags: E=(nt*4+ks)*64+lane, uint4 each
__global__ __launch_bounds__(256) void pv_prep(
    const float* __restrict__ bmr, const float* __restrict__ bmi,
    const float* __restrict__ c2pr, const float* __restrict__ c2pi,
    float* __restrict__ ws)
{
  const int tid = threadIdx.x;
  const int blk = blockIdx.x;
  if (blk == 0) {
    // dsinv[k] = 1/clip(sum_f bmr[f,k])  (trace-normalized diag sums to 1)
    __shared__ float sds[256];
    int k = tid & 63, part = tid >> 6;
    float s = 0.f;
    if (k < NBAND_) {
      const float* col = bmr + k;
      #pragma unroll 16
      for (int f = part * 128; f < part * 128 + 128; f++) s += col[f * 40];
    }
    sds[tid] = s;
    __syncthreads();
    if (tid < NBAND_) {
      float t = sds[tid] + sds[tid + 64] + sds[tid + 128] + sds[tid + 192];
      ws[tid] = 1.0f / fmaxf(t, 1e-20f);
    }
  } else if (blk <= 48) {
    // band-projection B fragments (identical mapping to R3 — verified)
    int F = (blk - 1) * 256 + tid;     // 0..12287
    int l = F & 63;
    int rest = F >> 6;
    int s5 = rest & 31;
    int gn = rest >> 5;
    int n = gn % 3, g = gn / 3;
    int k = n * 16 + (l & 15);
    unsigned dw[4];
    #pragma unroll
    for (int t2 = 0; t2 < 4; t2++) {
      float v0 = 0.f, v1 = 0.f;
      if (k < NBAND_) {
        int kd = s5 * 32 + (l >> 4) * 8 + 2 * t2;
        int f = kd >> 1;
        if (g == 0) { v0 = bmr[f * 40 + k]; v1 = -bmi[f * 40 + k]; }
        else        { v0 = bmi[f * 40 + k]; v1 =  bmr[f * 40 + k]; }
      }
      dw[t2] = pkbf(v0, v1);
    }
    ((uint4*)((char*)ws + 1024))[F] = make_uint4(dw[0], dw[1], dw[2], dw[3]);
  } else {
    // epilogue B fragments: B2[kd][p], kd=2c+e: e=0 -> c2pr[p][c], e=1 -> -c2pi[p][c]
    int F2 = (blk - 49) * 256 + tid;   // 0..1023
    int lane = F2 & 63, E = F2 >> 6;
    int nt = E >> 2, ks = E & 3;
    int n = lane & 15, quad = lane >> 4;
    int p = nt * 16 + n;
    unsigned dw[4];
    #pragma unroll
    for (int t2 = 0; t2 < 4; t2++) {
      int c = ks * 16 + quad * 4 + t2;
      dw[t2] = pkbf(c2pr[p * 64 + c], -c2pi[p * 64 + c]);
    }
    ((uint4*)((char*)ws + 197632))[E * 64 + lane] = make_uint4(dw[0], dw[1], dw[2], dw[3]);
  }
}

// LDS: vsh float2[8][514] = 32,896 B (epilogue overlays bcsh[48][66] f2 + dsinv[48])
__global__ __launch_bounds__(256, 4) void pv_main(
    const float* __restrict__ br, const float* __restrict__ bi,
    const float* __restrict__ ws, float* __restrict__ out)
{
  __shared__ __align__(16) float smem[8224];
  float2* vsh = (float2*)smem;

  const int bt  = blockIdx.x;
  const int tid = threadIdx.x;
  const float* pr  = br + (size_t)bt * (NCH_ * NBIN_);
  const float* pim = bi + (size_t)bt * (NCH_ * NBIN_);

  // ---- fused phase A: one pass over x; trace + per-channel phasor in registers ----
  #pragma unroll
  for (int fs = 0; fs < 2; fs++) {
    const int f = tid + fs * 256;
    const int fm = (f == 0) ? 0 : ((f == 511) ? 509 : f - 1);
    const int fp = (f == 0) ? 2 : ((f == 511) ? 511 : f + 1);
    float tr = 0.f;
    float t1[8], t2[8];
    #pragma unroll
    for (int c = 0; c < 8; c++) {
      const float* cr = pr + c * 512;
      const float* ci = pim + c * 512;
      float xr = cr[f],   xi = ci[f];
      float xrm = cr[fm], xim = ci[fm];
      float xrp = cr[fp], xip = ci[fp];
      tr = fmaf(xr, xr, tr); tr = fmaf(xi, xi, tr);
      float Gr = fmaf(xrm, xrp,  xim * xip);      // conj(x[fm]) * x[fp]
      float Gi = fmaf(xrm, xip, -(xim * xrp));
      float am = fmaxf(fmaxf(fabsf(Gr), fabsf(Gi)), 1e-30f);
      float rc = __builtin_amdgcn_rcpf(am);
      float q1 = Gr * rc, q2 = Gi * rc;
      float n2 = fmaf(q1, q1, q2 * q2);
      float rn = __builtin_amdgcn_rsqf(n2);
      bool ok = n2 > 0.f;
      float ur = ok ? q1 * rn : 1.f;
      float ui = ok ? q2 * rn : 0.f;
      float mg = __builtin_amdgcn_sqrtf(fmaf(xr, xr, xi * xi));
      t1[c] = mg * ur; t2[c] = mg * ui;
    }
    float scv = __builtin_amdgcn_rsqf(fmaxf(tr, 1e-20f));
    #pragma unroll
    for (int c = 0; c < 8; c++)
      vsh[c * 514 + f] = make_float2(t1[c] * scv, t2[c] * scv);
  }
  __syncthreads();

  // ---- band GEMM: C[p][k] = sum_f (v_i*conj(v_j))[f] * bm[f][k], bf16 MFMA ----
  const int w    = tid >> 6;
  const int lane = tid & 63;
  const int m16  = lane & 15;
  const int quad = lane >> 4;
  const int p    = w * 16 + m16;
  const int ich  = p >> 3, jch = p & 7;
  const float4* Av = (const float4*)(vsh + ich * 514 + quad * 4);
  const float4* Bv = (const float4*)(vsh + jch * 514 + quad * 4);
  const float4* BF = ((const float4*)((const char*)ws + 1024)) + lane;

  float4v acc[6];
  #pragma unroll
  for (int g = 0; g < 6; g++) acc[g] = (float4v){0.f, 0.f, 0.f, 0.f};

  float4 curB[6], nxtB[6];
  #pragma unroll
  for (int g = 0; g < 6; g++) curB[g] = BF[(g * 32) * 64];

  #pragma unroll 2
  for (int s = 0; s < 32; s++) {
    if (s < 31) {
      #pragma unroll
      for (int g = 0; g < 6; g++) nxtB[g] = BF[(g * 32 + s + 1) * 64];
    }
    float4 a01 = Av[s * 8], a23 = Av[s * 8 + 1];
    float4 b01 = Bv[s * 8], b23 = Bv[s * 8 + 1];
    float ar0 = fmaf(a01.x, b01.x,  a01.y * b01.y);
    float ai0 = fmaf(a01.y, b01.x, -(a01.x * b01.y));
    float ar1 = fmaf(a01.z, b01.z,  a01.w * b01.w);
    float ai1 = fmaf(a01.w, b01.z, -(a01.z * b01.w));
    float ar2 = fmaf(a23.x, b23.x,  a23.y * b23.y);
    float ai2 = fmaf(a23.y, b23.x, -(a23.x * b23.y));
    float ar3 = fmaf(a23.z, b23.z,  a23.w * b23.w);
    float ai3 = fmaf(a23.w, b23.z, -(a23.z * b23.w));
    uint4 au = make_uint4(pkbf(ar0, ai0), pkbf(ar1, ai1),
                          pkbf(ar2, ai2), pkbf(ar3, ai3));
    short8 afrag = __builtin_bit_cast(short8, au);
    #pragma unroll
    for (int g = 0; g < 6; g++) {
      short8 bfrag = __builtin_bit_cast(short8, curB[g]);
      acc[g] = __builtin_amdgcn_mfma_f32_16x16x32_bf16(afrag, bfrag, acc[g], 0, 0, 0);
    }
    #pragma unroll
    for (int g = 0; g < 6; g++) curB[g] = nxtB[g];
  }

  // preload epilogue B-frags (ready after the barrier)
  const uint4* EF = ((const uint4*)((const char*)ws + 197632)) + (w * 4) * 64 + lane;
  uint4 eb[4];
  #pragma unroll
  for (int ks = 0; ks < 4; ks++) eb[ks] = EF[ks * 64];

  // ---- epilogue GEMM: pv[k][p] = Re(sum_c c2p[p][c]*bc[k][c]) via bf16 MFMA ----
  __syncthreads();                    // vsh dead
  float2* bcsh = (float2*)smem;       // [48][66]
  float*  dssh = smem + 6336;         // [48]
  #pragma unroll
  for (int n = 0; n < 3; n++) {
    int k = n * 16 + m16;
    #pragma unroll
    for (int r = 0; r < 4; r++) {
      int c = w * 16 + quad * 4 + r;
      bcsh[k * 66 + c] = make_float2(acc[n][r], acc[3 + n][r]);
    }
  }
  if (tid < 48) dssh[tid] = (tid < NBAND_) ? ws[tid] : 0.f;
  __syncthreads();

  float4v eacc[3];
  #pragma unroll
  for (int mt = 0; mt < 3; mt++) eacc[mt] = (float4v){0.f, 0.f, 0.f, 0.f};
  #pragma unroll
  for (int ks = 0; ks < 4; ks++) {
    short8 bfrag = __builtin_bit_cast(short8, eb[ks]);
    #pragma unroll
    for (int mt = 0; mt < 3; mt++) {
      const float4* Ae = (const float4*)(bcsh + (mt * 16 + m16) * 66 + ks * 16 + quad * 4);
      float4 w0 = Ae[0], w1 = Ae[1];
      uint4 au2 = make_uint4(pkbf(w0.x, w0.y), pkbf(w0.z, w0.w),
                             pkbf(w1.x, w1.y), pkbf(w1.z, w1.w));
      short8 af2 = __builtin_bit_cast(short8, au2);
      eacc[mt] = __builtin_amdgcn_mfma_f32_16x16x32_bf16(af2, bfrag, eacc[mt], 0, 0, 0);
    }
  }
  // store: row k = mt*16+quad*4+r, col p = w*16+m16
  float* op = out + (size_t)bt * (NBAND_ * NPV_);
  #pragma unroll
  for (int mt = 0; mt < 3; mt++) {
    const float4* dv4 = (const float4*)(dssh + mt * 16 + quad * 4);
    float4 dv = dv4[0];
    float dva[4] = {dv.x, dv.y, dv.z, dv.w};
    #pragma unroll
    for (int r = 0; r < 4; r++) {
      int k = mt * 16 + quad * 4 + r;
      if (k < NBAND_)
        op[k * 64 + w * 16 + m16] = eacc[mt][r] * dva[r];
    }
  }
}

// ---------------- IIR: chunked scan, 320 blocks x 256 thr, chunk=25 ----------------
__global__ __launch_bounds__(256) void pv_iir3(float* __restrict__ z,
                                               const float* __restrict__ tau)
{
  __shared__ float gsh[16][16];
  const int pg = blockIdx.x & 3;
  const int bk = blockIdx.x >> 2;
  const int k = bk % NBAND_;
  const int b = bk / NBAND_;
  const float a  = tau[k];
  const float om = 1.0f - a;
  const int c  = threadIdx.x >> 4;
  const int pl = threadIdx.x & 15;
  const int p  = pg * 16 + pl;
  const size_t stride = (size_t)NBAND_ * 64;
  size_t idx0 = (size_t)b * (T_ * NBAND_ * 64) + (size_t)(c * 25) * stride + k * 64 + p;

  float y[25];
  float accv = 0.f;
  #pragma unroll
  for (int i = 0; i < 25; i++) {
    float v = z[idx0 + (size_t)i * stride];
    accv = fmaf(a, accv, om * v);
    y[i] = accv;
  }
  gsh[c][pl] = accv;
  __syncthreads();
  float a2 = a * a, a8 = a2 * a2 * a2 * a2, a16 = a8 * a8;
  float A = a16 * a8 * a;                   // a^25
  float H = 0.f;
  #pragma unroll
  for (int d = 0; d < 15; d++) {
    if (d < c) H = fmaf(A, H, gsh[d][pl]);
  }
  float wp = a;
  #pragma unroll
  for (int i = 0; i < 25; i++) {
    z[idx0 + (size_t)i * stride] = fmaf(wp, H, y[i]);
    wp *= a;
  }
}

extern "C" void kernel_launch(void* const* d_in, const int* in_sizes, int n_in,
                              void* d_out, int out_size, void* d_ws, size_t ws_size,
                              hipStream_t stream)
{
  const float* br   = (const float*)d_in[0];
  const float* bi   = (const float*)d_in[1];
  const float* bmr  = (const float*)d_in[2];
  const float* bmi  = (const float*)d_in[3];
  const float* c2pr = (const float*)d_in[4];
  const float* c2pi = (const float*)d_in[5];
  const float* tau  = (const float*)d_in[6];
  float* out = (float*)d_out;
  float* ws  = (float*)d_ws;

  hipLaunchKernelGGL(pv_prep, dim3(53), dim3(256), 0, stream,
                     bmr, bmi, c2pr, c2pi, ws);
  hipLaunchKernelGGL(pv_main, dim3(B_ * T_), dim3(256), 0, stream,
                     br, bi, ws, out);
  hipLaunchKernelGGL(pv_iir3, dim3(B_ * NBAND_ * 4), dim3(256), 0, stream,
                     out, tau);
}